// Round 3
// baseline (265.167 us; speedup 1.0000x reference)
//
#include <hip/hip_runtime.h>
#include <hip/hip_bf16.h>

#define B_  4
#define S_  2048
#define E_  1024
#define H_  16
#define DH_ 64
#define M_  (B_*S_)    // 8192 rows
#define HD_ (H_*DH_)   // 1024

typedef unsigned short u16;
typedef __attribute__((ext_vector_type(8))) __bf16 bf16x8;
typedef __attribute__((ext_vector_type(4))) __bf16 bf16x4;
typedef __attribute__((ext_vector_type(4))) float  f32x4;

#if __has_builtin(__builtin_amdgcn_exp2f)
#define EXP2F __builtin_amdgcn_exp2f
#else
#define EXP2F __builtin_exp2f
#endif

// softmax scale folded into Q at QKV epilogue: 1/sqrt(64) * log2(e)
#define QSCALE 0.18033688011112042f

// ---- async global->LDS, 16B per lane ----
__device__ __forceinline__ void g2l16(const void* g, void* l) {
  __builtin_amdgcn_global_load_lds(
      (const __attribute__((address_space(1))) void*)g,
      (__attribute__((address_space(3))) void*)l, 16, 0, 0);
}

// RNE float -> bf16 bits (scalar path, used in prep only)
__device__ __forceinline__ u16 f2bf(float f) {
  union { float f; unsigned u; } v; v.f = f;
  unsigned r = v.u + 0x7FFFu + ((v.u >> 16) & 1u);
  return (u16)(r >> 16);
}

// ---------------- fused prep: cvt_x | pack_wqkv | pack_wo ----------------
__global__ __launch_bounds__(256) void prep_kernel(
    const float* __restrict__ x, const float* __restrict__ Wq,
    const float* __restrict__ Wk, const float* __restrict__ Wv,
    const float* __restrict__ Wo,
    u16* __restrict__ xb, u16* __restrict__ wqkvT, u16* __restrict__ woT) {
  __shared__ u16 tile[64][66];
  const int blk = blockIdx.x, tid = threadIdx.x;
  if (blk < 8192) {
    int i = blk * 256 + tid;
    float4 v = ((const float4*)x)[i];
    ushort4 o;
    o.x = f2bf(v.x); o.y = f2bf(v.y); o.z = f2bf(v.z); o.w = f2bf(v.w);
    ((ushort4*)xb)[i] = o;
  } else if (blk < 8960) {
    int b2 = blk - 8192;
    int p = b2 >> 8, h = (b2 >> 4) & 15, e0 = (b2 & 15) * 64;
    const float* src = (p == 0 ? Wq : (p == 1 ? Wk : Wv)) + h * (E_ * DH_);
#pragma unroll
    for (int r = 0; r < 16; ++r) {
      int idx = r * 256 + tid;
      int el = idx >> 6, d = idx & 63;
      tile[el][d] = f2bf(src[(e0 + el) * DH_ + d]);
    }
    __syncthreads();
    u16* dst = wqkvT + (p * HD_ + h * DH_) * E_;
#pragma unroll
    for (int r = 0; r < 16; ++r) {
      int idx = r * 256 + tid;
      int d = idx >> 6, el = idx & 63;
      dst[d * E_ + e0 + el] = tile[el][d];
    }
  } else {
    int b3 = blk - 8960;
    int c0 = (b3 >> 4) * 64, e0 = (b3 & 15) * 64;
#pragma unroll
    for (int r = 0; r < 16; ++r) {
      int idx = r * 256 + tid;
      int cl = idx >> 6, el = idx & 63;
      tile[cl][el] = f2bf(Wo[(c0 + cl) * E_ + e0 + el]);
    }
    __syncthreads();
#pragma unroll
    for (int r = 0; r < 16; ++r) {
      int idx = r * 256 + tid;
      int er = idx >> 6, cl = idx & 63;
      woT[(e0 + er) * HD_ + c0 + cl] = tile[cl][er];
    }
  }
}

// ---------------- QKV GEMM, 8-phase-style schedule ----------------
// C[M][3072] = xb[M][1024] * wqkvT[3072][1024]^T
// Tile 128(M) x 256(N), BK=64, 512 thr = 8 waves (2M x 4N), per-wave 64x64.
// LDS 96 KiB: As[2] 16KB each | Bs[2] 32KB each (double buffer).
// Schedule per K-tile: 2 phases x {ds_read frags; 2x global_load_lds;
//   s_barrier; lgkmcnt(0); setprio(1); 16 MFMA; setprio(0); s_barrier}
// Boundary: stage next-next A into just-freed buffer, s_waitcnt vmcnt(2)
// (counted — never 0 in steady state), s_barrier.
// Epilogue: proven LDS-round-trip (Q/K row-major, V directly as V^T).
__global__ __launch_bounds__(512, 2) void gemm_qkv_kernel(
    const u16* __restrict__ A, const u16* __restrict__ Bt,
    const float* __restrict__ b0, const float* __restrict__ b1,
    const float* __restrict__ b2,
    u16* __restrict__ oQ, u16* __restrict__ oK, u16* __restrict__ oV) {
  constexpr int K = 1024;
  __shared__ __align__(16) u16 smem[49152];   // 96 KiB
  const int tid = threadIdx.x;
  const int lane = tid & 63, wv = tid >> 6;
  const int wm = wv >> 2, wn = wv & 3;        // 2 x 4 wave grid
  const int q4 = lane >> 4, lm = lane & 15;

  // XCD-aware bijective swizzle: 768 blocks, 96 per XCD
  const int bid = blockIdx.x;
  const int wg = (bid & 7) * 96 + (bid >> 3);
  const int tileN = (wg % 12) * 256;
  const int tileM = (wg / 12) * 128;

  // staging addresses (pass p covers rows p*64 .. p*64+63)
  const int sr = tid >> 3;
  const int swz = ((tid & 7) ^ (sr & 7)) * 8;
  const u16* gA = A + (size_t)(tileM + sr) * K + swz;
  const u16* gB = Bt + (size_t)(tileN + sr) * K + swz;

#define STG_A(c, p, kk) g2l16(gA + (size_t)(p) * 64 * K + (kk), \
                              smem + (c) * 8192 + (p) * 4096 + tid * 8)
#define STG_B(c, p, kk) g2l16(gB + (size_t)(p) * 64 * K + (kk), \
                              smem + 16384 + (c) * 16384 + (p) * 4096 + tid * 8)

  // fragment offsets; row&7 == lm&7, ks toggles via XOR 32
  const int xb_ = (q4 ^ (lm & 7)) * 8;
  int aoffs[4], boffs[4];
#pragma unroll
  for (int i = 0; i < 4; ++i) aoffs[i] = (wm * 64 + i * 16 + lm) * 64 + xb_;
#pragma unroll
  for (int j = 0; j < 4; ++j) boffs[j] = (wn * 64 + j * 16 + lm) * 64 + xb_;

  f32x4 acc[4][4] = {};

  // prologue: tile0 fully (6 loads) + tile1 A (2 loads); keep 2 in flight
  STG_A(0, 0, 0); STG_A(0, 1, 0);
  STG_B(0, 0, 0); STG_B(0, 1, 0); STG_B(0, 2, 0); STG_B(0, 3, 0);
  STG_A(1, 0, 64); STG_A(1, 1, 64);
  asm volatile("s_waitcnt vmcnt(2)" ::: "memory");
  __builtin_amdgcn_s_barrier();
  asm volatile("" ::: "memory");

  for (int kt = 0; kt < 16; ++kt) {
    const int cur = kt & 1, nxt = cur ^ 1;
    const u16* Asb = smem + cur * 8192;
    const u16* Bsb = smem + 16384 + cur * 16384;
    const int kn = (kt + 1) * 64;
    bf16x8 af[4], bfr[4];
    // ---- phase 1 (ks = 0) ----
#pragma unroll
    for (int i = 0; i < 4; ++i) af[i] = *(const bf16x8*)(Asb + aoffs[i]);
#pragma unroll
    for (int j = 0; j < 4; ++j) bfr[j] = *(const bf16x8*)(Bsb + boffs[j]);
    if (kt < 15) { STG_B(nxt, 0, kn); STG_B(nxt, 1, kn); }
    __builtin_amdgcn_s_barrier();
    asm volatile("s_waitcnt lgkmcnt(0)" ::: "memory");
    __builtin_amdgcn_s_setprio(1);
#pragma unroll
    for (int i = 0; i < 4; ++i)
#pragma unroll
      for (int j = 0; j < 4; ++j)
        acc[i][j] = __builtin_amdgcn_mfma_f32_16x16x32_bf16(af[i], bfr[j], acc[i][j], 0, 0, 0);
    __builtin_amdgcn_s_setprio(0);
    __builtin_amdgcn_s_barrier();
    // ---- phase 2 (ks = 1) ----
#pragma unroll
    for (int i = 0; i < 4; ++i) af[i] = *(const bf16x8*)(Asb + (aoffs[i] ^ 32));
#pragma unroll
    for (int j = 0; j < 4; ++j) bfr[j] = *(const bf16x8*)(Bsb + (boffs[j] ^ 32));
    if (kt < 15) { STG_B(nxt, 2, kn); STG_B(nxt, 3, kn); }
    __builtin_amdgcn_s_barrier();
    asm volatile("s_waitcnt lgkmcnt(0)" ::: "memory");
    __builtin_amdgcn_s_setprio(1);
#pragma unroll
    for (int i = 0; i < 4; ++i)
#pragma unroll
      for (int j = 0; j < 4; ++j)
        acc[i][j] = __builtin_amdgcn_mfma_f32_16x16x32_bf16(af[i], bfr[j], acc[i][j], 0, 0, 0);
    __builtin_amdgcn_s_setprio(0);
    __builtin_amdgcn_s_barrier();
    // ---- boundary: stage A of tile kt+2 into the just-freed buffer ----
    if (kt < 14) {
      STG_A(cur, 0, kn + 64); STG_A(cur, 1, kn + 64);
      asm volatile("s_waitcnt vmcnt(2)" ::: "memory");
    } else {
      asm volatile("s_waitcnt vmcnt(0)" ::: "memory");
    }
    __builtin_amdgcn_s_barrier();
    asm volatile("" ::: "memory");
  }
#undef STG_A
#undef STG_B

  // ---- epilogue: LDS round-trip for coalesced 16B stores ----
  u16* TT = smem;
  const int ccb = tileN & 1023;
  const int proj = tileN >> 10;               // uniform per block
  const float scl = (proj == 0 ? QSCALE : 1.0f);
  const float* bp = (proj == 0 ? b0 : (proj == 1 ? b1 : b2));
#pragma unroll
  for (int j = 0; j < 4; ++j) {
    const int ncl = wn * 64 + j * 16 + lm;
    const float bs = bp[ccb + ncl];
#pragma unroll
    for (int i = 0; i < 4; ++i) {
      const int m0 = wm * 64 + i * 16 + q4 * 4;
      f32x4 vv;
#pragma unroll
      for (int r = 0; r < 4; ++r) vv[r] = (acc[i][j][r] + bs) * scl;
      bf16x4 ov = __builtin_convertvector(vv, bf16x4);
      if (proj < 2) {
        // orientation A: (m, n) at m*256 + (n ^ 8*(m&31))
        ushort4 us = *(ushort4*)&ov;
        TT[(m0 + 0) * 256 + (ncl ^ (8 * ((m0 + 0) & 31)))] = us.x;
        TT[(m0 + 1) * 256 + (ncl ^ (8 * ((m0 + 1) & 31)))] = us.y;
        TT[(m0 + 2) * 256 + (ncl ^ (8 * ((m0 + 2) & 31)))] = us.z;
        TT[(m0 + 3) * 256 + (ncl ^ (8 * ((m0 + 3) & 31)))] = us.w;
      } else {
        // orientation B: (n, m) at n*128 + (m ^ 8*(n&15))
        *(bf16x4*)(TT + ncl * 128 + (m0 ^ (8 * (ncl & 15)))) = ov;
      }
    }
  }
  __syncthreads();
  if (proj < 2) {
    u16* optr = (proj == 0 ? oQ : oK);
#pragma unroll
    for (int it = 0; it < 8; ++it) {
      int seg = it * 512 + tid;
      int ml = seg >> 5, sc = (seg & 31) * 8;
      uint4 val = *(const uint4*)(TT + ml * 256 + (sc ^ (8 * (ml & 31))));
      *(uint4*)(optr + (size_t)(tileM + ml) * 1024 + ccb + sc) = val;
    }
  } else {
    const int bb = tileM >> 11, s0v = tileM & 2047;
#pragma unroll
    for (int it = 0; it < 8; ++it) {
      int seg = it * 512 + tid;
      int ccl = seg >> 4, sc = (seg & 15) * 8;
      uint4 val = *(const uint4*)(TT + ccl * 128 + (sc ^ (8 * (ccl & 15))));
      int cc = ccb + ccl, hh = cc >> 6, dd = cc & 63;
      *(uint4*)(oV + ((size_t)(bb * 16 + hh) * 64 + dd) * 2048 + s0v + sc) = val;
    }
  }
}

// ---------------- GEMM: C[M][N] = A[M][K] * Bt[N][K]^T, K = 1024, BK = 64 ----
// MODE 1: out-proj epilogue (b0=bo; bias + fp32 direct store)
template <int MODE>
__global__ __launch_bounds__(256) void gemm_bt_kernel(
    const u16* __restrict__ A, const u16* __restrict__ Bt,
    const float* __restrict__ b0, const float* __restrict__ b1,
    const float* __restrict__ b2,
    u16* __restrict__ oQ, u16* __restrict__ oK, u16* __restrict__ oV,
    float* __restrict__ oF) {
  constexpr int K = 1024;
  __shared__ __align__(16) u16 smem[2 * 128 * 64];   // As | Bs; reused as C-tile
  u16* As = smem;
  u16* Bs = smem + 128 * 64;
  const int tid = threadIdx.x;
  const int lane = tid & 63, wv = tid >> 6;
  const int wm = (wv >> 1) * 64, wn = (wv & 1) * 64;
  const int q4 = lane >> 4, lm = lane & 15;
  const int tileM = blockIdx.y * 128, tileN = blockIdx.x * 128;

  const u16* gA[4]; const u16* gB[4]; u16* lA[4]; u16* lB[4];
#pragma unroll
  for (int rr = 0; rr < 4; ++rr) {
    int c = rr * 256 + tid;
    int r = c >> 3, sw = ((c & 7) ^ (r & 7)) * 8;
    gA[rr] = A + (size_t)(tileM + r) * K + sw;
    gB[rr] = Bt + (size_t)(tileN + r) * K + sw;
    lA[rr] = As + c * 8;
    lB[rr] = Bs + c * 8;
  }

  f32x4 acc[4][4] = {};

  int aoff[2][4], boff[2][4];
#pragma unroll
  for (int ks = 0; ks < 2; ++ks) {
#pragma unroll
    for (int i = 0; i < 4; ++i) {
      int ra = wm + i * 16 + lm;
      aoff[ks][i] = ra * 64 + (((ks * 4 + q4) ^ (ra & 7)) * 8);
      int rb = wn + i * 16 + lm;
      boff[ks][i] = rb * 64 + (((ks * 4 + q4) ^ (rb & 7)) * 8);
    }
  }

  for (int k0 = 0; k0 < K; k0 += 64) {
#pragma unroll
    for (int rr = 0; rr < 4; ++rr) {
      g2l16(gA[rr] + k0, lA[rr]);
      g2l16(gB[rr] + k0, lB[rr]);
    }
    __syncthreads();
#pragma unroll
    for (int ks = 0; ks < 2; ++ks) {
      bf16x8 af[4], bf[4];
#pragma unroll
      for (int i = 0; i < 4; ++i) af[i] = *(const bf16x8*)(As + aoff[ks][i]);
#pragma unroll
      for (int j = 0; j < 4; ++j) bf[j] = *(const bf16x8*)(Bs + boff[ks][j]);
#pragma unroll
      for (int i = 0; i < 4; ++i)
#pragma unroll
        for (int j = 0; j < 4; ++j)
          acc[i][j] = __builtin_amdgcn_mfma_f32_16x16x32_bf16(af[i], bf[j], acc[i][j], 0, 0, 0);
    }
    __syncthreads();
  }

  if (MODE == 1) {
#pragma unroll
    for (int j = 0; j < 4; ++j) {
      int n = tileN + wn + j * 16 + lm;
      float bs = b0[n];
#pragma unroll
      for (int i = 0; i < 4; ++i) {
        int m0 = tileM + wm + i * 16 + q4 * 4;
#pragma unroll
        for (int r = 0; r < 4; ++r) oF[(m0 + r) * HD_ + n] = acc[i][j][r] + bs;
      }
    }
  } else {
    u16* TT = smem;
    const int ccb = tileN & 1023;
    const int proj = tileN >> 10;
    const float scl = (proj == 0 ? QSCALE : 1.0f);
    const float* bp = (proj == 0 ? b0 : (proj == 1 ? b1 : b2));
#pragma unroll
    for (int j = 0; j < 4; ++j) {
      int ncl = wn + j * 16 + lm;
      float bs = bp[ccb + ncl];
#pragma unroll
      for (int i = 0; i < 4; ++i) {
        int m0 = wm + i * 16 + q4 * 4;
        f32x4 vv;
#pragma unroll
        for (int r = 0; r < 4; ++r) vv[r] = (acc[i][j][r] + bs) * scl;
        bf16x4 ov = __builtin_convertvector(vv, bf16x4);
        if (proj < 2) {
          ushort4 us = *(ushort4*)&ov;
          TT[(m0 + 0) * 128 + (ncl ^ (8 * ((m0 + 0) & 15)))] = us.x;
          TT[(m0 + 1) * 128 + (ncl ^ (8 * ((m0 + 1) & 15)))] = us.y;
          TT[(m0 + 2) * 128 + (ncl ^ (8 * ((m0 + 2) & 15)))] = us.z;
          TT[(m0 + 3) * 128 + (ncl ^ (8 * ((m0 + 3) & 15)))] = us.w;
        } else {
          *(bf16x4*)(TT + ncl * 128 + (m0 ^ (8 * (ncl & 15)))) = ov;
        }
      }
    }
    __syncthreads();
    if (proj < 2) {
      u16* optr = (proj == 0 ? oQ : oK);
#pragma unroll
      for (int rr = 0; rr < 8; ++rr) {
        int seg = rr * 256 + tid;
        int ml = seg >> 4, sc = (seg & 15) * 8;
        uint4 val = *(const uint4*)(TT + ml * 128 + (sc ^ (8 * (ml & 15))));
        *(uint4*)(optr + (size_t)(tileM + ml) * 1024 + ccb + sc) = val;
      }
    } else {
      const int bb = tileM >> 11, s0 = tileM & 2047;
#pragma unroll
      for (int rr = 0; rr < 8; ++rr) {
        int seg = rr * 256 + tid;
        int ccl = seg >> 4, sc = (seg & 15) * 8;
        int cc = ccb + ccl;
        int hh = cc >> 6, dd = cc & 63;
        uint4 val = *(const uint4*)(TT + ccl * 128 + (sc ^ (8 * (ccl & 15))));
        *(uint4*)(oV + ((size_t)(bb * 16 + hh) * 64 + dd) * 2048 + s0 + sc) = val;
      }
    }
  }
}

// ---------------- flash attention (R8 proven config) ----------------
// Block: 256 q-rows of one (b,h); wave wv owns q-rows [wv*64, wv*64+64), all keys.
// K/V double-buffered in LDS via global_load_lds (one barrier per tile).
// KEY PERMUTATION: K rows staged at LDS slot s = kb*16+q4*4+r hold logical key
// kperm(s) = (kb&1)*32 + q4*8 + (kb>>1)*4 + r. The S^T-MFMA C-layout output IS
// the PV A-fragment layout per-lane; V keeps sequential key order. P never
// touches LDS.
// REGISTER RULE (R6, R9 failures): unified VGPR+AGPR demand is ~170+; any
// launch_bounds tighter than (256,2) forces a spill storm. Keep (256,2).
__global__ __launch_bounds__(256, 2) void flash_kernel(
    const u16* __restrict__ Q, const u16* __restrict__ Kb,
    const u16* __restrict__ Vt, u16* __restrict__ Z) {
  __shared__ __align__(16) u16 Ks[2][64 * 64];   // [slot][d] swizzled, key-permuted
  __shared__ __align__(16) u16 Vs[2][64 * 64];   // [d][key] swizzled, sequential
  const int tid = threadIdx.x, lane = tid & 63, wv = tid >> 6;
  const int q4 = lane >> 4, lm = lane & 15;

  const int bid = blockIdx.x;
  const int bh = bid >> 3, qt = bid & 7;         // 8 consecutive blocks share (b,h) K/V
  const int b = bh >> 4, h = bh & 15;

  const u16* qbase = Q + ((size_t)(b * S_ + qt * 256)) * HD_ + h * DH_;
  const u16* kbase = Kb + (size_t)b * S_ * HD_ + h * DH_;
  const u16* vbase = Vt + ((size_t)(b * H_ + h)) * DH_ * S_;
  u16* zbase = Z + ((size_t)(b * S_ + qt * 256)) * HD_ + h * DH_;

  const int c0 = tid,       r0 = c0 >> 3, s0 = ((c0 & 7) ^ (r0 & 7)) * 8;
  const int c1 = tid + 256, r1 = c1 >> 3, s1 = ((c1 & 7) ^ (r1 & 7)) * 8;
  const int kr0 = ((r0 >> 4) & 1) * 32 + ((r0 >> 2) & 3) * 8 + (r0 >> 5) * 4 + (r0 & 3);
  const int kr1 = ((r1 >> 4) & 1) * 32 + ((r1 >> 2) & 3) * 8 + (r1 >> 5) * 4 + (r1 & 3);

  bf16x8 qf[4][2];
#pragma unroll
  for (int qs = 0; qs < 4; ++qs)
#pragma unroll
    for (int dc = 0; dc < 2; ++dc)
      qf[qs][dc] = *(const bf16x8*)(qbase + (wv * 64 + qs * 16 + lm) * HD_ + dc * 32 + q4 * 8);

  const bf16x8 ones = {(__bf16)1.f, (__bf16)1.f, (__bf16)1.f, (__bf16)1.f,
                       (__bf16)1.f, (__bf16)1.f, (__bf16)1.f, (__bf16)1.f};

  int koff[4][2], voff[2][4];
#pragma unroll
  for (int kb = 0; kb < 4; ++kb)
#pragma unroll
    for (int dc = 0; dc < 2; ++dc) {
      int row = kb * 16 + lm;
      koff[kb][dc] = row * 64 + (((dc * 4 + q4) ^ (row & 7)) * 8);
    }
#pragma unroll
  for (int ck = 0; ck < 2; ++ck)
#pragma unroll
    for (int db = 0; db < 4; ++db) {
      int row = db * 16 + lm;
      voff[ck][db] = row * 64 + (((ck * 4 + q4) ^ (row & 7)) * 8);
    }

  f32x4 oacc[4][4] = {};
  f32x4 liacc[4] = {};

  {
    g2l16(kbase + kr0 * HD_ + s0, Ks[0] + c0 * 8);
    g2l16(kbase + kr1 * HD_ + s1, Ks[0] + c1 * 8);
    g2l16(vbase + r0 * S_ + s0, Vs[0] + c0 * 8);
    g2l16(vbase + r1 * S_ + s1, Vs[0] + c1 * 8);
  }

  for (int t = 0; t < 32; ++t) {
    const int pb = t & 1;
    __syncthreads();
    if (t < 31) {
      const u16* kt = kbase + (size_t)(t + 1) * 64 * HD_;
      const u16* vt = vbase + (t + 1) * 64;
      g2l16(kt + kr0 * HD_ + s0, Ks[1 - pb] + c0 * 8);
      g2l16(kt + kr1 * HD_ + s1, Ks[1 - pb] + c1 * 8);
      g2l16(vt + r0 * S_ + s0, Vs[1 - pb] + c0 * 8);
      g2l16(vt + r1 * S_ + s1, Vs[1 - pb] + c1 * 8);
    }
    const u16* Kp = Ks[pb];
    const u16* Vp = Vs[pb];

#pragma unroll
    for (int ck = 0; ck < 2; ++ck) {
      bf16x8 ka0 = *(const bf16x8*)(Kp + koff[ck][0]);
      bf16x8 ka1 = *(const bf16x8*)(Kp + koff[ck][1]);
      bf16x8 kb0 = *(const bf16x8*)(Kp + koff[ck + 2][0]);
      bf16x8 kb1 = *(const bf16x8*)(Kp + koff[ck + 2][1]);
      bf16x8 pf[4];
#pragma unroll
      for (int qs = 0; qs < 4; ++qs) {
        f32x4 sa = {}, sb = {};
        sa = __builtin_amdgcn_mfma_f32_16x16x32_bf16(ka0, qf[qs][0], sa, 0, 0, 0);
        sa = __builtin_amdgcn_mfma_f32_16x16x32_bf16(ka1, qf[qs][1], sa, 0, 0, 0);
        sb = __builtin_amdgcn_mfma_f32_16x16x32_bf16(kb0, qf[qs][0], sb, 0, 0, 0);
        sb = __builtin_amdgcn_mfma_f32_16x16x32_bf16(kb1, qf[qs][1], sb, 0, 0, 0);
        f32x4 pa, pb2;
#pragma unroll
        for (int r = 0; r < 4; ++r) { pa[r] = EXP2F(sa[r]); pb2[r] = EXP2F(sb[r]); }
        bf16x4 la = __builtin_convertvector(pa, bf16x4);
        bf16x4 lb = __builtin_convertvector(pb2, bf16x4);
        pf[qs] = __builtin_shufflevector(la, lb, 0, 1, 2, 3, 4, 5, 6, 7);
      }
#pragma unroll
      for (int qs = 0; qs < 4; ++qs)
        liacc[qs] = __builtin_amdgcn_mfma_f32_16x16x32_bf16(pf[qs], ones, liacc[qs], 0, 0, 0);
#pragma unroll
      for (int db = 0; db < 4; ++db) {
        bf16x8 vf = *(const bf16x8*)(Vp + voff[ck][db]);
#pragma unroll
        for (int qs = 0; qs < 4; ++qs)
          oacc[qs][db] = __builtin_amdgcn_mfma_f32_16x16x32_bf16(pf[qs], vf, oacc[qs][db], 0, 0, 0);
      }
    }
  }

  // ---- normalize + store (wave owns its 64 q-rows; li is in-lane) ----
#pragma unroll
  for (int qs = 0; qs < 4; ++qs) {
    float rin[4];
#pragma unroll
    for (int r = 0; r < 4; ++r) rin[r] = 1.f / liacc[qs][r];
#pragma unroll
    for (int db = 0; db < 4; ++db) {
      f32x4 vv;
#pragma unroll
      for (int r = 0; r < 4; ++r) vv[r] = oacc[qs][db][r] * rin[r];
      bf16x4 ov = __builtin_convertvector(vv, bf16x4);
      ushort4 us = *(ushort4*)&ov;
      int m0 = wv * 64 + qs * 16 + q4 * 4;
      zbase[(m0 + 0) * HD_ + db * 16 + lm] = us.x;
      zbase[(m0 + 1) * HD_ + db * 16 + lm] = us.y;
      zbase[(m0 + 2) * HD_ + db * 16 + lm] = us.z;
      zbase[(m0 + 3) * HD_ + db * 16 + lm] = us.w;
    }
  }
}

// ---------------- host ----------------
extern "C" void kernel_launch(void* const* d_in, const int* in_sizes, int n_in,
                              void* d_out, int out_size, void* d_ws, size_t ws_size,
                              hipStream_t stream) {
  const float* x  = (const float*)d_in[0];
  const float* Wq = (const float*)d_in[1];
  const float* bq = (const float*)d_in[2];
  const float* Wk = (const float*)d_in[3];
  const float* bk = (const float*)d_in[4];
  const float* Wv = (const float*)d_in[5];
  const float* bv = (const float*)d_in[6];
  const float* Wo = (const float*)d_in[7];
  const float* bo = (const float*)d_in[8];
  float* out = (float*)d_out;

  char* w = (char*)d_ws;
  u16*   xb    = (u16*)w;   w += (size_t)M_ * E_ * 2;
  u16*   wqkvT = (u16*)w;   w += (size_t)3 * HD_ * E_ * 2;
  u16*   woT   = (u16*)w;   w += (size_t)E_ * HD_ * 2;
  u16*   qB    = (u16*)w;   w += (size_t)M_ * HD_ * 2;
  u16*   kB    = (u16*)w;   w += (size_t)M_ * HD_ * 2;
  u16*   vT    = (u16*)w;   w += (size_t)M_ * HD_ * 2;     // V^T written by gemm0
  u16*   zB    = (u16*)w;   w += (size_t)M_ * HD_ * 2;

  prep_kernel<<<dim3(9216), 256, 0, stream>>>(x, Wq, Wk, Wv, Wo, xb, wqkvT, woT);
  gemm_qkv_kernel<<<dim3(768), 512, 0, stream>>>(xb, wqkvT, bq, bk, bv, qB, kB, vT);
  flash_kernel<<<dim3(512), 256, 0, stream>>>(qB, kB, vT, zB);
  gemm_bt_kernel<1><<<dim3(8, 64), 256, 0, stream>>>(zB, woT, bo, nullptr, nullptr,
                                                     nullptr, nullptr, nullptr, out);
}

// Round 4
// 261.487 us; speedup vs baseline: 1.0141x; 1.0141x over previous
//
#include <hip/hip_runtime.h>
#include <hip/hip_bf16.h>

#define B_  4
#define S_  2048
#define E_  1024
#define H_  16
#define DH_ 64
#define M_  (B_*S_)    // 8192 rows
#define HD_ (H_*DH_)   // 1024

typedef unsigned short u16;
typedef __attribute__((ext_vector_type(8))) __bf16 bf16x8;
typedef __attribute__((ext_vector_type(4))) __bf16 bf16x4;
typedef __attribute__((ext_vector_type(4))) float  f32x4;

#if __has_builtin(__builtin_amdgcn_exp2f)
#define EXP2F __builtin_amdgcn_exp2f
#else
#define EXP2F __builtin_exp2f
#endif

// softmax scale folded into Q at QKV epilogue: 1/sqrt(64) * log2(e)
#define QSCALE 0.18033688011112042f

// ---- async global->LDS, 16B per lane ----
__device__ __forceinline__ void g2l16(const void* g, void* l) {
  __builtin_amdgcn_global_load_lds(
      (const __attribute__((address_space(1))) void*)g,
      (__attribute__((address_space(3))) void*)l, 16, 0, 0);
}

// RNE float -> bf16 bits (scalar path, used in prep only)
__device__ __forceinline__ u16 f2bf(float f) {
  union { float f; unsigned u; } v; v.f = f;
  unsigned r = v.u + 0x7FFFu + ((v.u >> 16) & 1u);
  return (u16)(r >> 16);
}

// ---------------- fused prep: cvt_x | pack_wqkv | pack_wo ----------------
__global__ __launch_bounds__(256) void prep_kernel(
    const float* __restrict__ x, const float* __restrict__ Wq,
    const float* __restrict__ Wk, const float* __restrict__ Wv,
    const float* __restrict__ Wo,
    u16* __restrict__ xb, u16* __restrict__ wqkvT, u16* __restrict__ woT) {
  __shared__ u16 tile[64][66];
  const int blk = blockIdx.x, tid = threadIdx.x;
  if (blk < 8192) {
    int i = blk * 256 + tid;
    float4 v = ((const float4*)x)[i];
    ushort4 o;
    o.x = f2bf(v.x); o.y = f2bf(v.y); o.z = f2bf(v.z); o.w = f2bf(v.w);
    ((ushort4*)xb)[i] = o;
  } else if (blk < 8960) {
    int b2 = blk - 8192;
    int p = b2 >> 8, h = (b2 >> 4) & 15, e0 = (b2 & 15) * 64;
    const float* src = (p == 0 ? Wq : (p == 1 ? Wk : Wv)) + h * (E_ * DH_);
#pragma unroll
    for (int r = 0; r < 16; ++r) {
      int idx = r * 256 + tid;
      int el = idx >> 6, d = idx & 63;
      tile[el][d] = f2bf(src[(e0 + el) * DH_ + d]);
    }
    __syncthreads();
    u16* dst = wqkvT + (p * HD_ + h * DH_) * E_;
#pragma unroll
    for (int r = 0; r < 16; ++r) {
      int idx = r * 256 + tid;
      int d = idx >> 6, el = idx & 63;
      dst[d * E_ + e0 + el] = tile[el][d];
    }
  } else {
    int b3 = blk - 8960;
    int c0 = (b3 >> 4) * 64, e0 = (b3 & 15) * 64;
#pragma unroll
    for (int r = 0; r < 16; ++r) {
      int idx = r * 256 + tid;
      int cl = idx >> 6, el = idx & 63;
      tile[cl][el] = f2bf(Wo[(c0 + cl) * E_ + e0 + el]);
    }
    __syncthreads();
#pragma unroll
    for (int r = 0; r < 16; ++r) {
      int idx = r * 256 + tid;
      int er = idx >> 6, cl = idx & 63;
      woT[(e0 + er) * HD_ + c0 + cl] = tile[cl][er];
    }
  }
}

// ---------------- GEMM: C[M][N] = A[M][K] * Bt[N][K]^T, K = 1024, BK = 64 ----
// MODE 0: QKV epilogue — bias, bf16, then LDS round-trip to emit 16B coalesced
//         stores. Q/K in [m][cc] orientation; V written DIRECTLY as V^T
//         [b,h,d,s] via [cc][m] orientation (no separate transpose kernel).
// MODE 1: out-proj epilogue (b0=bo; bias + fp32 direct store)
// R3 NOTE: a 128x256 2-phase/setprio/counted-vmcnt variant (1 block/CU) was
// measured == this kernel (265.2 vs 261.5 total); partial 8-phase grafts
// don't pay without the full template. Keep this 3-blocks/CU structure.
template <int MODE>
__global__ __launch_bounds__(256) void gemm_bt_kernel(
    const u16* __restrict__ A, const u16* __restrict__ Bt,
    const float* __restrict__ b0, const float* __restrict__ b1,
    const float* __restrict__ b2,
    u16* __restrict__ oQ, u16* __restrict__ oK, u16* __restrict__ oV,
    float* __restrict__ oF) {
  constexpr int K = 1024;
  __shared__ __align__(16) u16 smem[2 * 128 * 64];   // As | Bs; reused as C-tile
  u16* As = smem;
  u16* Bs = smem + 128 * 64;
  const int tid = threadIdx.x;
  const int lane = tid & 63, wv = tid >> 6;
  const int wm = (wv >> 1) * 64, wn = (wv & 1) * 64;
  const int q4 = lane >> 4, lm = lane & 15;
  const int tileM = blockIdx.y * 128, tileN = blockIdx.x * 128;

  const u16* gA[4]; const u16* gB[4]; u16* lA[4]; u16* lB[4];
#pragma unroll
  for (int rr = 0; rr < 4; ++rr) {
    int c = rr * 256 + tid;
    int r = c >> 3, sw = ((c & 7) ^ (r & 7)) * 8;
    gA[rr] = A + (size_t)(tileM + r) * K + sw;
    gB[rr] = Bt + (size_t)(tileN + r) * K + sw;
    lA[rr] = As + c * 8;
    lB[rr] = Bs + c * 8;
  }

  f32x4 acc[4][4] = {};

  int aoff[2][4], boff[2][4];
#pragma unroll
  for (int ks = 0; ks < 2; ++ks) {
#pragma unroll
    for (int i = 0; i < 4; ++i) {
      int ra = wm + i * 16 + lm;
      aoff[ks][i] = ra * 64 + (((ks * 4 + q4) ^ (ra & 7)) * 8);
      int rb = wn + i * 16 + lm;
      boff[ks][i] = rb * 64 + (((ks * 4 + q4) ^ (rb & 7)) * 8);
    }
  }

  for (int k0 = 0; k0 < K; k0 += 64) {
#pragma unroll
    for (int rr = 0; rr < 4; ++rr) {
      g2l16(gA[rr] + k0, lA[rr]);
      g2l16(gB[rr] + k0, lB[rr]);
    }
    __syncthreads();
#pragma unroll
    for (int ks = 0; ks < 2; ++ks) {
      bf16x8 af[4], bf[4];
#pragma unroll
      for (int i = 0; i < 4; ++i) af[i] = *(const bf16x8*)(As + aoff[ks][i]);
#pragma unroll
      for (int j = 0; j < 4; ++j) bf[j] = *(const bf16x8*)(Bs + boff[ks][j]);
#pragma unroll
      for (int i = 0; i < 4; ++i)
#pragma unroll
        for (int j = 0; j < 4; ++j)
          acc[i][j] = __builtin_amdgcn_mfma_f32_16x16x32_bf16(af[i], bf[j], acc[i][j], 0, 0, 0);
    }
    __syncthreads();
  }

  if (MODE == 1) {
#pragma unroll
    for (int j = 0; j < 4; ++j) {
      int n = tileN + wn + j * 16 + lm;
      float bs = b0[n];
#pragma unroll
      for (int i = 0; i < 4; ++i) {
        int m0 = tileM + wm + i * 16 + q4 * 4;
#pragma unroll
        for (int r = 0; r < 4; ++r) oF[(m0 + r) * HD_ + n] = acc[i][j][r] + bs;
      }
    }
  } else {
    // ---- LDS round-trip epilogue (after final barrier, smem is free) ----
    u16* TT = smem;                        // 128 x 128 bf16, swizzled
    const int ccb = tileN & 1023;
    const int proj = tileN >> 10;          // uniform per block
    const float scl = (proj == 0 ? QSCALE : 1.0f);
    const float* bp = (proj == 0 ? b0 : (proj == 1 ? b1 : b2));
#pragma unroll
    for (int j = 0; j < 4; ++j) {
      int ncl = wn + j * 16 + lm;
      float bs = bp[ccb + ncl];
#pragma unroll
      for (int i = 0; i < 4; ++i) {
        int m0 = wm + i * 16 + q4 * 4;
        f32x4 vv;
#pragma unroll
        for (int r = 0; r < 4; ++r) vv[r] = (acc[i][j][r] + bs) * scl;
        bf16x4 ov = __builtin_convertvector(vv, bf16x4);
        if (proj < 2) {
          // orientation A: element (ml, ccl) at ml*128 + (ccl ^ 8*(ml&15))
          ushort4 us = *(ushort4*)&ov;
          TT[(m0 + 0) * 128 + (ncl ^ (8 * ((m0 + 0) & 15)))] = us.x;
          TT[(m0 + 1) * 128 + (ncl ^ (8 * ((m0 + 1) & 15)))] = us.y;
          TT[(m0 + 2) * 128 + (ncl ^ (8 * ((m0 + 2) & 15)))] = us.z;
          TT[(m0 + 3) * 128 + (ncl ^ (8 * ((m0 + 3) & 15)))] = us.w;
        } else {
          // orientation B: element (ccl, ml) at ccl*128 + (ml ^ 8*(ccl&15))
          *(bf16x4*)(TT + ncl * 128 + (m0 ^ (8 * (ncl & 15)))) = ov;  // b64
        }
      }
    }
    __syncthreads();
    if (proj < 2) {
      u16* optr = (proj == 0 ? oQ : oK);
#pragma unroll
      for (int rr = 0; rr < 8; ++rr) {
        int seg = rr * 256 + tid;
        int ml = seg >> 4, sc = (seg & 15) * 8;
        uint4 val = *(const uint4*)(TT + ml * 128 + (sc ^ (8 * (ml & 15))));
        *(uint4*)(optr + (size_t)(tileM + ml) * 1024 + ccb + sc) = val;
      }
    } else {
      const int bb = tileM >> 11, s0 = tileM & 2047;
#pragma unroll
      for (int rr = 0; rr < 8; ++rr) {
        int seg = rr * 256 + tid;
        int ccl = seg >> 4, sc = (seg & 15) * 8;
        int cc = ccb + ccl;
        int hh = cc >> 6, dd = cc & 63;
        uint4 val = *(const uint4*)(TT + ccl * 128 + (sc ^ (8 * (ccl & 15))));
        *(uint4*)(oV + ((size_t)(bb * 16 + hh) * 64 + dd) * 2048 + s0 + sc) = val;
      }
    }
  }
}

// ---------------- flash attention — R4: occupancy-doubled config ----------------
// R3 counters: MfmaUtil 40 / VALUBusy 36 / Occupancy 17.8% — latency-bound at
// 2 blocks/CU (grid 512). Fix: 32 q-rows per wave, 128 q-rows per 256-thr
// block, grid 1024 -> 3-4 blocks/CU. Register diet: oacc/liacc/qf halved,
// koff/voff arrays folded to 2 base offsets + compile-time imm offsets
// (koff[kb][dc] = kb*1024 + base[dc]; voff[ck][db] = db*1024 + base[ck],
// valid because row&7 == lm&7). T5 setprio around li+PV MFMA cluster.
// KEY PERMUTATION unchanged: K rows staged at LDS slot s = kb*16+q4*4+r hold
// logical key kperm(s) = (kb&1)*32 + q4*8 + (kb>>1)*4 + r. The S^T-MFMA
// C-layout output IS the PV A-fragment layout per-lane; V keeps sequential
// key order. P never touches LDS.
// REGISTER RULE (R6, R9 failures): do not force launch_bounds tighter than
// (256,2) — spill storm. Occupancy gain here comes from GRID, not the cap.
__global__ __launch_bounds__(256, 2) void flash_kernel(
    const u16* __restrict__ Q, const u16* __restrict__ Kb,
    const u16* __restrict__ Vt, u16* __restrict__ Z) {
  __shared__ __align__(16) u16 Ks[2][64 * 64];   // [slot][d] swizzled, key-permuted
  __shared__ __align__(16) u16 Vs[2][64 * 64];   // [d][key] swizzled, sequential
  const int tid = threadIdx.x, lane = tid & 63, wv = tid >> 6;
  const int q4 = lane >> 4, lm = lane & 15;

  const int bid = blockIdx.x;
  const int bh = bid >> 4, qt = bid & 15;        // 16 consecutive blocks share (b,h) K/V
  const int b = bh >> 4, h = bh & 15;

  const u16* qbase = Q + ((size_t)(b * S_ + qt * 128)) * HD_ + h * DH_;
  const u16* kbase = Kb + (size_t)b * S_ * HD_ + h * DH_;
  const u16* vbase = Vt + ((size_t)(b * H_ + h)) * DH_ * S_;
  u16* zbase = Z + ((size_t)(b * S_ + qt * 128)) * HD_ + h * DH_;

  const int c0 = tid,       r0 = c0 >> 3, s0 = ((c0 & 7) ^ (r0 & 7)) * 8;
  const int c1 = tid + 256, r1 = c1 >> 3, s1 = ((c1 & 7) ^ (r1 & 7)) * 8;
  const int kr0 = ((r0 >> 4) & 1) * 32 + ((r0 >> 2) & 3) * 8 + (r0 >> 5) * 4 + (r0 & 3);
  const int kr1 = ((r1 >> 4) & 1) * 32 + ((r1 >> 2) & 3) * 8 + (r1 >> 5) * 4 + (r1 & 3);

  bf16x8 qf[2][2];
#pragma unroll
  for (int qs = 0; qs < 2; ++qs)
#pragma unroll
    for (int dc = 0; dc < 2; ++dc)
      qf[qs][dc] = *(const bf16x8*)(qbase + (wv * 32 + qs * 16 + lm) * HD_ + dc * 32 + q4 * 8);

  const bf16x8 ones = {(__bf16)1.f, (__bf16)1.f, (__bf16)1.f, (__bf16)1.f,
                       (__bf16)1.f, (__bf16)1.f, (__bf16)1.f, (__bf16)1.f};

  // fragment base offsets (d-chunk 0 / 1); kb/db contribute imm kb*1024/db*1024
  const int base0 = lm * 64 + ((q4 ^ (lm & 7)) * 8);
  const int base1 = lm * 64 + (((4 + q4) ^ (lm & 7)) * 8);

  f32x4 oacc[2][4] = {};
  f32x4 liacc[2] = {};

  {
    g2l16(kbase + kr0 * HD_ + s0, Ks[0] + c0 * 8);
    g2l16(kbase + kr1 * HD_ + s1, Ks[0] + c1 * 8);
    g2l16(vbase + r0 * S_ + s0, Vs[0] + c0 * 8);
    g2l16(vbase + r1 * S_ + s1, Vs[0] + c1 * 8);
  }

  for (int t = 0; t < 32; ++t) {
    const int pb = t & 1;
    __syncthreads();
    if (t < 31) {
      const u16* kt = kbase + (size_t)(t + 1) * 64 * HD_;
      const u16* vt = vbase + (t + 1) * 64;
      g2l16(kt + kr0 * HD_ + s0, Ks[1 - pb] + c0 * 8);
      g2l16(kt + kr1 * HD_ + s1, Ks[1 - pb] + c1 * 8);
      g2l16(vt + r0 * S_ + s0, Vs[1 - pb] + c0 * 8);
      g2l16(vt + r1 * S_ + s1, Vs[1 - pb] + c1 * 8);
    }
    const u16* Kp = Ks[pb];
    const u16* Vp = Vs[pb];

#pragma unroll
    for (int ck = 0; ck < 2; ++ck) {
      bf16x8 ka0 = *(const bf16x8*)(Kp + ck * 1024 + base0);
      bf16x8 ka1 = *(const bf16x8*)(Kp + ck * 1024 + base1);
      bf16x8 kb0 = *(const bf16x8*)(Kp + (ck + 2) * 1024 + base0);
      bf16x8 kb1 = *(const bf16x8*)(Kp + (ck + 2) * 1024 + base1);
      bf16x8 pf[2];
#pragma unroll
      for (int qs = 0; qs < 2; ++qs) {
        f32x4 sa = {}, sb = {};
        sa = __builtin_amdgcn_mfma_f32_16x16x32_bf16(ka0, qf[qs][0], sa, 0, 0, 0);
        sa = __builtin_amdgcn_mfma_f32_16x16x32_bf16(ka1, qf[qs][1], sa, 0, 0, 0);
        sb = __builtin_amdgcn_mfma_f32_16x16x32_bf16(kb0, qf[qs][0], sb, 0, 0, 0);
        sb = __builtin_amdgcn_mfma_f32_16x16x32_bf16(kb1, qf[qs][1], sb, 0, 0, 0);
        f32x4 pa, pb2;
#pragma unroll
        for (int r = 0; r < 4; ++r) { pa[r] = EXP2F(sa[r]); pb2[r] = EXP2F(sb[r]); }
        bf16x4 la = __builtin_convertvector(pa, bf16x4);
        bf16x4 lb = __builtin_convertvector(pb2, bf16x4);
        pf[qs] = __builtin_shufflevector(la, lb, 0, 1, 2, 3, 4, 5, 6, 7);
      }
      const int vsel = ck ? base1 : base0;
      __builtin_amdgcn_s_setprio(1);
#pragma unroll
      for (int qs = 0; qs < 2; ++qs)
        liacc[qs] = __builtin_amdgcn_mfma_f32_16x16x32_bf16(pf[qs], ones, liacc[qs], 0, 0, 0);
#pragma unroll
      for (int db = 0; db < 4; ++db) {
        bf16x8 vf = *(const bf16x8*)(Vp + db * 1024 + vsel);
#pragma unroll
        for (int qs = 0; qs < 2; ++qs)
          oacc[qs][db] = __builtin_amdgcn_mfma_f32_16x16x32_bf16(pf[qs], vf, oacc[qs][db], 0, 0, 0);
      }
      __builtin_amdgcn_s_setprio(0);
    }
  }

  // ---- normalize + store (wave owns its 32 q-rows; li is in-lane) ----
#pragma unroll
  for (int qs = 0; qs < 2; ++qs) {
    float rin[4];
#pragma unroll
    for (int r = 0; r < 4; ++r) rin[r] = 1.f / liacc[qs][r];
#pragma unroll
    for (int db = 0; db < 4; ++db) {
      f32x4 vv;
#pragma unroll
      for (int r = 0; r < 4; ++r) vv[r] = oacc[qs][db][r] * rin[r];
      bf16x4 ov = __builtin_convertvector(vv, bf16x4);
      ushort4 us = *(ushort4*)&ov;
      int m0 = wv * 32 + qs * 16 + q4 * 4;
      zbase[(m0 + 0) * HD_ + db * 16 + lm] = us.x;
      zbase[(m0 + 1) * HD_ + db * 16 + lm] = us.y;
      zbase[(m0 + 2) * HD_ + db * 16 + lm] = us.z;
      zbase[(m0 + 3) * HD_ + db * 16 + lm] = us.w;
    }
  }
}

// ---------------- host ----------------
extern "C" void kernel_launch(void* const* d_in, const int* in_sizes, int n_in,
                              void* d_out, int out_size, void* d_ws, size_t ws_size,
                              hipStream_t stream) {
  const float* x  = (const float*)d_in[0];
  const float* Wq = (const float*)d_in[1];
  const float* bq = (const float*)d_in[2];
  const float* Wk = (const float*)d_in[3];
  const float* bk = (const float*)d_in[4];
  const float* Wv = (const float*)d_in[5];
  const float* bv = (const float*)d_in[6];
  const float* Wo = (const float*)d_in[7];
  const float* bo = (const float*)d_in[8];
  float* out = (float*)d_out;

  char* w = (char*)d_ws;
  u16*   xb    = (u16*)w;   w += (size_t)M_ * E_ * 2;
  u16*   wqkvT = (u16*)w;   w += (size_t)3 * HD_ * E_ * 2;
  u16*   woT   = (u16*)w;   w += (size_t)E_ * HD_ * 2;
  u16*   qB    = (u16*)w;   w += (size_t)M_ * HD_ * 2;
  u16*   kB    = (u16*)w;   w += (size_t)M_ * HD_ * 2;
  u16*   vT    = (u16*)w;   w += (size_t)M_ * HD_ * 2;     // V^T written by gemm0
  u16*   zB    = (u16*)w;   w += (size_t)M_ * HD_ * 2;

  prep_kernel<<<dim3(9216), 256, 0, stream>>>(x, Wq, Wk, Wv, Wo, xb, wqkvT, woT);
  gemm_bt_kernel<0><<<dim3(24, 64), 256, 0, stream>>>(xb, wqkvT, bq, bk, bv,
                                                      qB, kB, vT, nullptr);
  flash_kernel<<<dim3(1024), 256, 0, stream>>>(qB, kB, vT, zB);
  gemm_bt_kernel<1><<<dim3(8, 64), 256, 0, stream>>>(zB, woT, bo, nullptr, nullptr,
                                                     nullptr, nullptr, nullptr, out);
}